// Round 3
// baseline (957.518 us; speedup 1.0000x reference)
//
#include <hip/hip_runtime.h>

// ---------------------------------------------------------------------------
// SCUNet shifted-window attention block (Swin 'SW' type), MI355X gfx950.
// b=4, H=W=256, C=256, WS=8 (p2=64 tokens/window), 8 heads x 32 dim.
//   x -> roll(-4,-4) -> window partition -> qkv GEMM -> per-window attention
//     (rel-pos bias + shift mask + softmax) -> merge (torch-faithful scramble)
//     -> out GEMM -> roll(+4,+4)
// Strategy: bf16 MFMA (16x16x32) for all three matmuls, fp32 softmax.
// R2 fix: Phase C wave mapping — each wave owns one FULL head (h = wv, all 8
// heads), iterating the query rows in two halves. R1 only computed heads 0-3.
// ---------------------------------------------------------------------------

typedef __attribute__((ext_vector_type(8))) short short8;   // 8 x bf16 fragment
typedef __attribute__((ext_vector_type(4))) float f32x4;    // MFMA accumulator

#define SCALE 0.17677669529663687f  // 1/sqrt(32)

__device__ __forceinline__ short f2bf(float f) {
  union { float f; unsigned u; } x; x.f = f;
  unsigned r = (x.u + 0x7fffu + ((x.u >> 16) & 1u)) >> 16;  // RNE
  return (short)r;
}

// ---------------------------------------------------------------------------
// K0: weight conversion fp32->bf16 + rel-pos bias table expansion [8][64][64]
// ---------------------------------------------------------------------------
__global__ void k_prep(const float* __restrict__ wq, const float* __restrict__ wo,
                       const float* __restrict__ rel,
                       short* __restrict__ wq_b, short* __restrict__ wo_b,
                       float* __restrict__ btab) {
  int i = blockIdx.x * 256 + threadIdx.x;
  if (i < 768 * 256) { wq_b[i] = f2bf(wq[i]); return; }
  int j = i - 768 * 256;
  if (j < 256 * 256) { wo_b[j] = f2bf(wo[j]); return; }
  int k = j - 256 * 256;
  if (k < 8 * 64 * 64) {
    int h = k >> 12, p = (k >> 6) & 63, q = k & 63;
    int pi = p >> 3, pj = p & 7, qi = q >> 3, qj = q & 7;
    btab[k] = rel[h * 225 + (pi - qi + 7) * 15 + (pj - qj + 7)];
  }
}

// ---------------------------------------------------------------------------
// K1: fused  shift + window + QKV GEMM + attention  -> aout (bf16, windowed)
// One block per (batch, window). 512 threads = 8 waves. 128 KB dynamic LDS:
//   xs  [64][256] bf16  (x window, swizzled)        32 KB   (reused as P bufs)
//   qs  [64][256] bf16  (q, scaled, swizzled)       32 KB
//   ks  [64][256] bf16                              32 KB
//   vsT [256][64] bf16  (v transposed, swizzled)    32 KB
// Swizzle: 16B-chunk index within a row XORed with (row&7) -> conflict-free
// ds_read_b128 MFMA fragment reads.
// ---------------------------------------------------------------------------
__global__ __launch_bounds__(512)
void k_winattn(const float* __restrict__ x, const short* __restrict__ wq,
               const float* __restrict__ bqkv, const float* __restrict__ btab,
               short* __restrict__ aout) {
  const int blk = blockIdx.x;
  const int bb = blk >> 10, win = blk & 1023;
  const int wy = win >> 5, wx = win & 31;
  const int tid = threadIdx.x;
  const int wv = tid >> 6, lane = tid & 63;
  const int lg = lane >> 4, l15 = lane & 15;

  extern __shared__ char smem[];
  char* xs  = smem;
  char* qs  = smem + 32768;
  char* ks  = smem + 65536;
  char* vsT = smem + 98304;

  // ---- Phase A: load shifted x window -> xs (bf16, swizzled) ----
  const float* xbase = x + (size_t)bb * (256u * 256u * 256u);
  #pragma unroll
  for (int it = 0; it < 16; ++it) {
    int s = it * 512 + tid;              // 8192 segments of 8 channels
    int row = s >> 5, kseg = s & 31;
    int pi = row >> 3, pj = row & 7;
    int gi = (wy * 8 + pi + 4) & 255;    // roll(-4): x_sh[i] = x[i+4]
    int gj = (wx * 8 + pj + 4) & 255;
    const float* gp = xbase + (size_t)(gi * 256 + gj) * 256 + kseg * 8;
    f32x4 f0 = *(const f32x4*)gp;
    f32x4 f1 = *(const f32x4*)(gp + 4);
    short8 sv;
    sv[0]=f2bf(f0[0]); sv[1]=f2bf(f0[1]); sv[2]=f2bf(f0[2]); sv[3]=f2bf(f0[3]);
    sv[4]=f2bf(f1[0]); sv[5]=f2bf(f1[1]); sv[6]=f2bf(f1[2]); sv[7]=f2bf(f1[3]);
    *(short8*)(xs + row * 512 + ((kseg ^ (row & 7)) << 4)) = sv;
  }
  __syncthreads();

  // ---- Phase B: QKV GEMM  C[64][768] = Xw @ Wqkv^T  (wave: 6 N-tiles) ----
  #pragma unroll
  for (int grp = 0; grp < 2; ++grp) {
    const int t0 = wv * 6 + grp * 3;
    f32x4 acc[3][4] = {};
    #pragma unroll
    for (int kk = 0; kk < 8; ++kk) {
      short8 a[4];
      const int cb = kk * 4 + lg;
      #pragma unroll
      for (int mt = 0; mt < 4; ++mt) {
        int row = mt * 16 + l15;
        a[mt] = *(const short8*)(xs + row * 512 + ((cb ^ (row & 7)) << 4));
      }
      #pragma unroll
      for (int u = 0; u < 3; ++u) {
        int r = (t0 + u) * 16 + l15;
        short8 b = *(const short8*)(wq + r * 256 + kk * 32 + lg * 8);
        #pragma unroll
        for (int mt = 0; mt < 4; ++mt)
          acc[u][mt] = __builtin_amdgcn_mfma_f32_16x16x32_bf16(a[mt], b, acc[u][mt], 0, 0, 0);
      }
    }
    // epilogue: route channels to qs / ks / vsT (bf16, swizzled)
    #pragma unroll
    for (int u = 0; u < 3; ++u) {
      int ch = (t0 + u) * 16 + l15;
      float bias = bqkv[ch];
      #pragma unroll
      for (int mt = 0; mt < 4; ++mt) {
        #pragma unroll
        for (int j = 0; j < 4; ++j) {
          int tok = mt * 16 + lg * 4 + j;
          float val = acc[u][mt][j] + bias;
          if (ch < 256) {
            *(short*)(qs + tok * 512 + ((((ch >> 3) ^ (tok & 7)) << 4) | ((ch & 7) * 2))) =
                f2bf(val * SCALE);
          } else if (ch < 512) {
            int c2 = ch - 256;
            *(short*)(ks + tok * 512 + ((((c2 >> 3) ^ (tok & 7)) << 4) | ((c2 & 7) * 2))) =
                f2bf(val);
          } else {
            int c2 = ch - 512;
            *(short*)(vsT + c2 * 128 + ((((tok >> 3) ^ (c2 & 7)) << 4) | ((tok & 7) * 2))) =
                f2bf(val);
          }
        }
      }
    }
  }
  __syncthreads();   // qkv visible; xs free -> reuse as per-wave P buffers

  // ---- Phase C: attention. One wave per head (h = wv), 2 query halves ----
  const int h = wv;
  char* ps = smem + wv * 4096;           // 32 rows x 128 B, swizzled
  const float* bt = btab + h * 4096;
  const bool maskI = (wy == 31), maskJ = (wx == 31);

  // K fragments (all 64 key tokens) — head-dependent only, reused both halves
  short8 bk[4];
  #pragma unroll
  for (int nt = 0; nt < 4; ++nt) {
    int row = nt * 16 + l15;
    bk[nt] = *(const short8*)(ks + row * 512 + (((h * 4 + lg) ^ (row & 7)) << 4));
  }
  // V fragments — head-dependent only, reused both halves
  short8 bv[2][2];
  #pragma unroll
  for (int kk = 0; kk < 2; ++kk)
    #pragma unroll
    for (int nt = 0; nt < 2; ++nt) {
      int ch = h * 32 + nt * 16 + l15;
      bv[kk][nt] = *(const short8*)(vsT + ch * 128 + (((kk * 4 + lg) ^ (ch & 7)) << 4));
    }

  short* ab = aout + ((size_t)(bb * 1024 + win) * 64) * 256;

  #pragma unroll
  for (int mh = 0; mh < 2; ++mh) {
    // QK^T : S[p][q] (2 M-tiles x 4 N-tiles, K=32 single MFMA step)
    f32x4 sacc[2][4] = {};
    short8 aq[2];
    #pragma unroll
    for (int m = 0; m < 2; ++m) {
      int row = (mh * 2 + m) * 16 + l15;
      aq[m] = *(const short8*)(qs + row * 512 + (((h * 4 + lg) ^ (row & 7)) << 4));
    }
    #pragma unroll
    for (int m = 0; m < 2; ++m)
      #pragma unroll
      for (int nt = 0; nt < 4; ++nt)
        sacc[m][nt] = __builtin_amdgcn_mfma_f32_16x16x32_bf16(aq[m], bk[nt], sacc[m][nt], 0, 0, 0);

    // bias + shift-mask + softmax (rows spread over 16 consecutive lanes)
    #pragma unroll
    for (int m = 0; m < 2; ++m) {
      #pragma unroll
      for (int j = 0; j < 4; ++j) {
        int p = (mh * 2 + m) * 16 + lg * 4 + j;
        int pi = p >> 3, pj = p & 7;
        float rmax = -3e38f;
        #pragma unroll
        for (int nt = 0; nt < 4; ++nt) {
          int qt = nt * 16 + l15;
          int qi = qt >> 3, qj = qt & 7;
          float sv = sacc[m][nt][j] + bt[p * 64 + qt];
          bool msk = (maskI && ((pi < 4) != (qi < 4))) || (maskJ && ((pj < 4) != (qj < 4)));
          sv = msk ? -3e38f : sv;
          sacc[m][nt][j] = sv;
          rmax = fmaxf(rmax, sv);
        }
        rmax = fmaxf(rmax, __shfl_xor(rmax, 1));
        rmax = fmaxf(rmax, __shfl_xor(rmax, 2));
        rmax = fmaxf(rmax, __shfl_xor(rmax, 4));
        rmax = fmaxf(rmax, __shfl_xor(rmax, 8));
        float rsum = 0.f;
        #pragma unroll
        for (int nt = 0; nt < 4; ++nt) {
          float e = __expf(sacc[m][nt][j] - rmax);
          sacc[m][nt][j] = e;
          rsum += e;
        }
        rsum += __shfl_xor(rsum, 1);
        rsum += __shfl_xor(rsum, 2);
        rsum += __shfl_xor(rsum, 4);
        rsum += __shfl_xor(rsum, 8);
        float inv = 1.0f / rsum;
        int prow = m * 16 + lg * 4 + j;      // row within wave's P buffer
        #pragma unroll
        for (int nt = 0; nt < 4; ++nt) {
          int qt = nt * 16 + l15;
          *(short*)(ps + prow * 128 + ((((qt >> 3) ^ (prow & 7)) << 4) | ((qt & 7) * 2))) =
              f2bf(sacc[m][nt][j] * inv);
        }
      }
    }

    // PV : out[p][d] = P @ V_h   (2 M-tiles x 2 N-tiles x 2 K-steps)
    f32x4 oacc[2][2] = {};
    #pragma unroll
    for (int kk = 0; kk < 2; ++kk) {
      short8 ap[2];
      #pragma unroll
      for (int m = 0; m < 2; ++m) {
        int ar = m * 16 + l15;
        ap[m] = *(const short8*)(ps + ar * 128 + (((kk * 4 + lg) ^ (ar & 7)) << 4));
      }
      #pragma unroll
      for (int m = 0; m < 2; ++m)
        #pragma unroll
        for (int nt = 0; nt < 2; ++nt)
          oacc[m][nt] = __builtin_amdgcn_mfma_f32_16x16x32_bf16(ap[m], bv[kk][nt], oacc[m][nt], 0, 0, 0);
    }

    // write attention output (bf16) in windowed layout [(bb,win), tok, ch]
    #pragma unroll
    for (int m = 0; m < 2; ++m)
      #pragma unroll
      for (int nt = 0; nt < 2; ++nt) {
        int ch = h * 32 + nt * 16 + l15;
        #pragma unroll
        for (int j = 0; j < 4; ++j) {
          int tok = mh * 32 + m * 16 + lg * 4 + j;
          ab[tok * 256 + ch] = f2bf(oacc[m][nt][j]);
        }
      }
  }
}

// ---------------------------------------------------------------------------
// K2: out-projection GEMM + torch-faithful batch/window scramble + roll(+4).
// Block g in [0,4096): reads window (bb = g&3, win = g>>2) from aout, writes
// to batch b2 = g>>10 at window (y = (g>>5)&31, x = g&31), spatial +4 roll.
// ---------------------------------------------------------------------------
__global__ __launch_bounds__(256)
void k_outproj(const short* __restrict__ aout, const short* __restrict__ wo,
               const float* __restrict__ bout, float* __restrict__ out) {
  const int g = blockIdx.x;
  const int win = g >> 2, bb = g & 3;
  const int b2 = g >> 10, y = (g >> 5) & 31, xw = g & 31;
  const int tid = threadIdx.x;
  const int wv = tid >> 6, lane = tid & 63;
  const int lg = lane >> 4, l15 = lane & 15;

  __shared__ char ys[32768];
  const short* src = aout + ((size_t)((bb << 10) | win) * 64) * 256;
  #pragma unroll
  for (int it = 0; it < 8; ++it) {
    int cidx = it * 256 + tid;           // 2048 16B chunks
    int row = cidx >> 5, kseg = cidx & 31;
    short8 v = *(const short8*)(src + row * 256 + kseg * 8);
    *(short8*)(ys + row * 512 + ((kseg ^ (row & 7)) << 4)) = v;
  }
  __syncthreads();

  f32x4 acc[4][4] = {};
  #pragma unroll
  for (int kk = 0; kk < 8; ++kk) {
    short8 a[4];
    const int cb = kk * 4 + lg;
    #pragma unroll
    for (int mt = 0; mt < 4; ++mt) {
      int row = mt * 16 + l15;
      a[mt] = *(const short8*)(ys + row * 512 + ((cb ^ (row & 7)) << 4));
    }
    #pragma unroll
    for (int u = 0; u < 4; ++u) {
      int r = wv * 64 + u * 16 + l15;
      short8 b = *(const short8*)(wo + r * 256 + kk * 32 + lg * 8);
      #pragma unroll
      for (int mt = 0; mt < 4; ++mt)
        acc[u][mt] = __builtin_amdgcn_mfma_f32_16x16x32_bf16(a[mt], b, acc[u][mt], 0, 0, 0);
    }
  }

  #pragma unroll
  for (int u = 0; u < 4; ++u) {
    int ch = wv * 64 + u * 16 + l15;
    float bias = bout[ch];
    #pragma unroll
    for (int mt = 0; mt < 4; ++mt) {
      #pragma unroll
      for (int j = 0; j < 4; ++j) {
        int tok = mt * 16 + lg * 4 + j;
        int pi = tok >> 3, pj = tok & 7;
        int oi = (y * 8 + pi + 4) & 255;   // roll(+4)
        int oj = (xw * 8 + pj + 4) & 255;
        out[((size_t)(b2 * 256 + oi) * 256 + oj) * 256 + ch] = acc[u][mt][j] + bias;
      }
    }
  }
}

// ---------------------------------------------------------------------------
extern "C" void kernel_launch(void* const* d_in, const int* in_sizes, int n_in,
                              void* d_out, int out_size, void* d_ws, size_t ws_size,
                              hipStream_t stream) {
  const float* x      = (const float*)d_in[0];
  const float* w_qkv  = (const float*)d_in[1];
  const float* b_qkv  = (const float*)d_in[2];
  const float* relpos = (const float*)d_in[3];
  const float* w_out  = (const float*)d_in[4];
  const float* b_out  = (const float*)d_in[5];
  float* out = (float*)d_out;

  // workspace layout (bytes): wq_b 393216 | wo_b 131072 | aout 134217728 | btab 131072
  short* wq_b = (short*)d_ws;
  short* wo_b = wq_b + 768 * 256;
  short* aout = wo_b + 256 * 256;
  float* btab = (float*)((char*)d_ws + (size_t)(768 * 256 + 256 * 256 + (size_t)4 * 1024 * 64 * 256) * 2);

  (void)hipFuncSetAttribute((const void*)k_winattn,
                            hipFuncAttributeMaxDynamicSharedMemorySize, 131072);

  k_prep<<<1152, 256, 0, stream>>>(w_qkv, w_out, relpos, wq_b, wo_b, btab);
  k_winattn<<<4096, 512, 131072, stream>>>(x, wq_b, b_qkv, btab, aout);
  k_outproj<<<4096, 256, 0, stream>>>(aout, wo_b, b_out, out);
}